// Round 13
// baseline (4720.620 us; speedup 1.0000x reference)
//
#include <hip/hip_runtime.h>
#include <stdint.h>

#define V_ 32000
#define E_ 512
#define H_ 1024
#define M_ 256
#define B_ 2
#define S_ 1024
#define GC_ 24

typedef unsigned short u16;
typedef unsigned int u32;
typedef unsigned long long u64;

typedef __attribute__((ext_vector_type(8))) short short8;
typedef __attribute__((ext_vector_type(4))) float floatx4;
typedef __attribute__((ext_vector_type(2))) float floatx2;
typedef __attribute__((ext_vector_type(2))) _Float16 halfx2;

__device__ __forceinline__ float bf2f(u16 u){ return __uint_as_float(((u32)u) << 16); }
__device__ __forceinline__ float bflo(u32 u){ return __uint_as_float(u << 16); }
__device__ __forceinline__ float bfhi(u32 u){ return __uint_as_float(u & 0xffff0000u); }
__device__ __forceinline__ u16 f2bf(float f){
  u32 u = __float_as_uint(f);
  u32 r = (u + 0x7fffu + ((u >> 16) & 1u)) >> 16;
  return (u16)r;
}
__device__ __forceinline__ float sigm(float x){ return 1.f / (1.f + __expf(-x)); }

// 2-wide f16 dot product accumulating into f32 (v_dot2_f32_f16); graceful fallback.
__device__ __forceinline__ float dot2f16(u32 a, u32 b, float c){
#if __has_builtin(__builtin_amdgcn_fdot2)
  return __builtin_amdgcn_fdot2(__builtin_bit_cast(halfx2, a),
                                __builtin_bit_cast(halfx2, b), c, false);
#else
  halfx2 av = __builtin_bit_cast(halfx2, a);
  halfx2 bv = __builtin_bit_cast(halfx2, b);
  return fmaf((float)av.y, (float)bv.y, fmaf((float)av.x, (float)bv.x, c));
#endif
}

// ---------------- dtype probe: low-u16-as-bf16 plausibility test on emb ----------------
__global__ __launch_bounds__(64) void detect_kernel(const u32* __restrict__ emb,
    int* __restrict__ flag, float* __restrict__ scal,
    const void* __restrict__ lam, const void* __restrict__ ms)
{
  int lane = threadIdx.x;
  int c = 0;
  for (int i = lane; i < 256; i += 64){
    u32 w = emb[i];
    float a = fabsf(__uint_as_float((w & 0xffffu) << 16));
    if (a > 1e-5f && a < 1.0f) c++;
  }
  #pragma unroll
  for (int o = 32; o; o >>= 1) c += __shfl_down(c, o, 64);
  if (lane == 0){
    int isf32 = (c < 128) ? 1 : 0;
    *flag = isf32;
    if (isf32) scal[0] = ((const float*)lam)[0];
    else {
      float v = bf2f(((const u16*)lam)[0]);
      scal[0] = (fabsf(v) <= 4.0f) ? v : ((const float*)lam)[0];
    }
    if (isf32) scal[1] = ((const float*)ms)[0];
    else {
      u16 a = ((const u16*)ms)[0];
      float v = bf2f(a);
      scal[1] = (a != 0 && fabsf(v) > 1e-4f && fabsf(v) < 1e4f) ? v : ((const float*)ms)[0];
    }
  }
}

// ---------------- merged canonicalization: all 15 tensors in ONE launch ----------------
struct ConvArgs { const void* s[15]; };

#define CONV_TOTAL 22191385
__global__ __launch_bounds__(256) void convall_kernel(ConvArgs a, char* __restrict__ ws,
                                                      const int* __restrict__ flag)
{
  static const int    ns[15]    = {16384000, 1572864, 3145728, 262144, 262144, 1024,
                                   524288, 3072, 3072, 256, 256, 1, 512, 32000, 24};
  static const size_t doffs[15] = {33280, 32801280, 35947008, 42238464, 42762752,
                                   43287040, 43289088, 44337664, 44343808, 44349952,
                                   44350464, 44350976, 44351232, 44352256, 44416512};
  int gid = blockIdx.x * 256 + threadIdx.x;
  if (gid >= CONV_TOTAL) return;
  int isf32 = *flag;
  int seg = -1, r = gid;
  #pragma unroll
  for (int k = 0; k < 15; k++){
    if (seg < 0){ if (r < ns[k]) seg = k; else r -= ns[k]; }
  }
  const void* src = a.s[seg];
  u16* dst = (u16*)(ws + doffs[seg]);
  if (seg == 2){   // W_hh -> f16 (GRU dot2 path)
    float v = isf32 ? ((const float*)src)[r] : bf2f(((const u16*)src)[r]);
    dst[r] = __builtin_bit_cast(u16, (_Float16)v);
  } else {         // bf16 canonical
    dst[r] = isf32 ? f2bf(((const float*)src)[r]) : ((const u16*)src)[r];
  }
}

// ---------------- smear: x' = emb[ids]; x'[t] += lam*sigmoid(x[t,:24]@smW)*x[t-1] ----------------
__global__ __launch_bounds__(64) void smear_kernel(const int* __restrict__ ids,
    const u16* __restrict__ emb, const u16* __restrict__ smW,
    const float* __restrict__ scal, u16* __restrict__ xs)
{
  int row = blockIdx.x;                 // b*S + t
  int t = row & (S_ - 1);
  int lane = threadIdx.x;
  int id = ids[row];
  const u16* er = emb + (size_t)id * E_;
  float sg = 0.f;
  if (t > 0){
    float p = 0.f;
    if (lane < GC_) p = bf2f(er[lane]) * bf2f(smW[lane]);
    #pragma unroll
    for (int o = 32; o; o >>= 1) p += __shfl_down(p, o, 64);
    float dot = __shfl(p, 0, 64);
    sg = scal[0] * sigm(dot);
  }
  uint4 cur = ((const uint4*)er)[lane];
  uint4 outv = cur;
  if (t > 0){
    const u16* ep = emb + (size_t)ids[row - 1] * E_;
    uint4 prv = ((const uint4*)ep)[lane];
    const u16* cu = (const u16*)&cur;
    const u16* pu = (const u16*)&prv;
    u16* po = (u16*)&outv;
    #pragma unroll
    for (int j = 0; j < 8; j++) po[j] = f2bf(bf2f(cu[j]) + sg * bf2f(pu[j]));
  }
  ((uint4*)(xs + (size_t)row * E_))[lane] = outv;
}

// ---------------- generic MFMA GEMM kernel (used for the pre-GRU xg GEMM) ----------------
template<bool OUT_BF16>
__global__ __launch_bounds__(256) void gemm_bt(
    const u16* __restrict__ A, const u16* __restrict__ Bm,
    const u16* __restrict__ bias, void* __restrict__ Cout,
    int K, int Ndim)
{
  int wave = threadIdx.x >> 6, lane = threadIdx.x & 63;
  int wm = wave >> 1, wn = wave & 1;
  int m0 = blockIdx.y * 128 + wm * 64;
  int n0 = blockIdx.x * 128 + wn * 64;
  int lrow = lane & 15, lq = lane >> 4;
  floatx4 acc[4][4];
  #pragma unroll
  for (int i = 0; i < 4; i++)
    #pragma unroll
    for (int j = 0; j < 4; j++) acc[i][j] = (floatx4)0.f;
  const u16* Ab = A + (size_t)(m0 + lrow) * K + lq * 8;
  const u16* Bb = Bm + (size_t)(n0 + lrow) * K + lq * 8;
  for (int k0 = 0; k0 < K; k0 += 32){
    short8 af[4], bfr[4];
    #pragma unroll
    for (int tt = 0; tt < 4; tt++)
      af[tt] = *(const short8*)(Ab + (size_t)tt * 16 * K + k0);
    #pragma unroll
    for (int tt = 0; tt < 4; tt++)
      bfr[tt] = *(const short8*)(Bb + (size_t)tt * 16 * K + k0);
    #pragma unroll
    for (int im = 0; im < 4; im++)
      #pragma unroll
      for (int in = 0; in < 4; in++)
        acc[im][in] = __builtin_amdgcn_mfma_f32_16x16x32_bf16(af[im], bfr[in], acc[im][in], 0, 0, 0);
  }
  #pragma unroll
  for (int in = 0; in < 4; in++){
    int n = n0 + in * 16 + lrow;
    float bv = bf2f(bias[n]);
    #pragma unroll
    for (int im = 0; im < 4; im++){
      int mb = m0 + im * 16 + lq * 4;
      #pragma unroll
      for (int r = 0; r < 4; r++){
        float v = acc[im][in][r] + bv;
        size_t off = (size_t)(mb + r) * Ndim + n;
        if (OUT_BF16) ((u16*)Cout)[off] = f2bf(v);
        else          ((float*)Cout)[off] = v;
      }
    }
  }
}

// ---------------- device-side 128x128 GEMM tile (gemm_bt body, callable by workers) ----------------
__device__ void tile_gemm(const u16* __restrict__ A, const u16* __restrict__ Bm,
                          const u16* __restrict__ bias, void* __restrict__ Cout,
                          int K, int Ndim, int tm0, int tn0, int wave, int lane, int outbf)
{
  int wm = wave >> 1, wn = wave & 1;
  int m0 = tm0 + wm * 64;
  int n0 = tn0 + wn * 64;
  int lrow = lane & 15, lq = lane >> 4;
  floatx4 acc[4][4];
  #pragma unroll
  for (int i = 0; i < 4; i++)
    #pragma unroll
    for (int j = 0; j < 4; j++) acc[i][j] = (floatx4)0.f;
  const u16* Ab = A + (size_t)(m0 + lrow) * K + lq * 8;
  const u16* Bb = Bm + (size_t)(n0 + lrow) * K + lq * 8;
  for (int k0 = 0; k0 < K; k0 += 32){
    short8 af[4], bfr[4];
    #pragma unroll
    for (int tt = 0; tt < 4; tt++)
      af[tt] = *(const short8*)(Ab + (size_t)tt * 16 * K + k0);
    #pragma unroll
    for (int tt = 0; tt < 4; tt++)
      bfr[tt] = *(const short8*)(Bb + (size_t)tt * 16 * K + k0);
    #pragma unroll
    for (int im = 0; im < 4; im++)
      #pragma unroll
      for (int in = 0; in < 4; in++)
        acc[im][in] = __builtin_amdgcn_mfma_f32_16x16x32_bf16(af[im], bfr[in], acc[im][in], 0, 0, 0);
  }
  #pragma unroll
  for (int in = 0; in < 4; in++){
    int n = n0 + in * 16 + lrow;
    float bv = bf2f(bias[n]);
    #pragma unroll
    for (int im = 0; im < 4; im++){
      int mb = m0 + im * 16 + lq * 4;
      #pragma unroll
      for (int r = 0; r < 4; r++){
        float v = acc[im][in][r] + bv;
        size_t off = (size_t)(mb + r) * Ndim + n;
        if (outbf) ((u16*)Cout)[off] = f2bf(v);
        else       ((float*)Cout)[off] = v;
      }
    }
  }
}

// ---------------- mega-kernel: gru (WGs 0-63) + sort (64-65) + shadow workers (66-255) ----------------
// gru: v10 session-best math unchanged; adds a release atomicAdd on prog[b*8+chunk]
//      every 128 steps (after states stores; vmcnt drained by the atomic's release).
// workers: static quad list (1072 quads), each quad = 4 128x128 no-LDS MFMA tiles on
//      the WG's 4 quarter-blocks (256 thr each, no intra-tile barriers). Deps via
//      acquire loads on {prog, hs_done, qkv_total}; posts via release stores after a
//      __syncthreads (which drains all waves' vmcnt). Quad list is chunk-major so
//      only chunk-7-gated work trails the gru end. No worker->gru waits: deadlock-free.
struct MegaArgs {
  const float* xg; const u16* Whh; const u16* bhh; u32* hslot; u16* states;
  const int* ids; int* sorted;
  const u16* Whe; const u16* bhe; u16* hs;
  const u16* Wq;  const u16* bq;  u16* qb;
  const u16* Wk;  const u16* bk;  u16* kb;
  const u16* emb; const u16* ob;  float* out;
  const u16* zbias; float* scores;
  u32* ctr;   // [0..15] prog (b*8+c, target 32), [16..31] hs_done, [32] qkv_total
};

__global__ __launch_bounds__(1024) void mega_kernel(MegaArgs a)
{
  const int tid = threadIdx.x;

  // ---------------- sort WGs ----------------
  __shared__ int arr[S_];
  if (blockIdx.x >= 64 && blockIdx.x < 66){
    int b = blockIdx.x - 64;
    arr[tid] = (a.ids[b * S_ + tid] << 11) | tid;
    __syncthreads();
    for (int k = 2; k <= S_; k <<= 1){
      for (int j = k >> 1; j > 0; j >>= 1){
        int ixj = tid ^ j;
        if (ixj > tid){
          int x = arr[tid], c = arr[ixj];
          bool dir = (tid & k) == 0;
          if (dir ? (x > c) : (x < c)){ arr[tid] = c; arr[ixj] = x; }
        }
        __syncthreads();
      }
    }
    a.sorted[b * S_ + tid] = arr[tid];
    return;
  }

  // ---------------- shadow workers ----------------
  if (blockIdx.x >= 66){
    const int wid = blockIdx.x - 66;
    const int qt = tid >> 8;           // quarter 0..3
    const int qtid = tid & 255;
    const int wave = qtid >> 6, lane = qtid & 63;
    u32* prog = a.ctr;
    u32* hsd  = a.ctr + 16;
    u32* qkvt = a.ctr + 32;
    for (int q = wid; q < 1072; q += 190){
      int type, mt = 0, nq = 0, sbb = 0, si = 0, sj0 = 0;
      if (q < 1040){
        int c = q / 130, r = q - c * 130;
        if (r < 2){ type = 0; mt = c + 8 * r; }                       // hs quad
        else if (r < 4){ type = 1; mt = c + 8 * (r - 2); }            // qkv quad
        else { type = 2; int rr = r - 4; mt = c + 8 * (rr / 63); nq = rr - (rr / 63) * 63; }
      } else {
        type = 3; int r = q - 1040; sbb = r >> 4;
        int qq = r & 15; si = qq >> 1; sj0 = (qq & 1) * 4;            // scores quad
      }
      if (tid == 0){
        if (type <= 1){
          while (__hip_atomic_load(&prog[mt], __ATOMIC_ACQUIRE, __HIP_MEMORY_SCOPE_AGENT) < 32u)
            __builtin_amdgcn_s_sleep(8);
        } else if (type == 2){
          while (__hip_atomic_load(&hsd[mt], __ATOMIC_ACQUIRE, __HIP_MEMORY_SCOPE_AGENT) == 0u)
            __builtin_amdgcn_s_sleep(8);
        } else {
          while (__hip_atomic_load(qkvt, __ATOMIC_ACQUIRE, __HIP_MEMORY_SCOPE_AGENT) < 16u)
            __builtin_amdgcn_s_sleep(8);
        }
      }
      __syncthreads();
      if (type == 0){
        tile_gemm(a.states, a.Whe, a.bhe, a.hs, H_, 512, mt * 128, qt * 128, wave, lane, 1);
      } else if (type == 1){
        if (qt < 2) tile_gemm(a.states, a.Wq, a.bq, a.qb, H_, M_, mt * 128, qt * 128, wave, lane, 1);
        else        tile_gemm(a.states, a.Wk, a.bk, a.kb, H_, M_, mt * 128, (qt - 2) * 128, wave, lane, 1);
      } else if (type == 2){
        int ntile = nq * 4 + qt;
        if (ntile < 250)
          tile_gemm(a.hs, a.emb, a.ob, a.out, E_, V_, mt * 128, ntile * 128, wave, lane, 0);
      } else {
        int j = sj0 + qt;
        tile_gemm(a.qb + (size_t)sbb * S_ * M_, a.kb + (size_t)sbb * S_ * M_, a.zbias,
                  a.scores + (size_t)sbb * S_ * S_, M_, S_, si * 128, j * 128, wave, lane, 0);
      }
      __syncthreads();   // drains all waves' stores (vmcnt) before the release post
      if (tid == 0){
        if (type == 0)
          __hip_atomic_store(&hsd[mt], 1u, __ATOMIC_RELEASE, __HIP_MEMORY_SCOPE_AGENT);
        else if (type == 1)
          __hip_atomic_fetch_add(qkvt, 1u, __ATOMIC_RELEASE, __HIP_MEMORY_SCOPE_AGENT);
      }
    }
    return;
  }

  // ---------------- gru WGs (v10 math, + per-128-step progress publish) ----------------
  const int b = blockIdx.x >> 5;
  const int ibase = (blockIdx.x & 31) * 32;
  const int kg = tid >> 5;
  const int il = tid & 31;
  const int i = ibase + il;
  const int w = tid >> 6;

  __shared__ u32   lds_hpk[2][H_ / 2];
  __shared__ float red[3][16][32];

  uint4 Wv[3][4];
  #pragma unroll
  for (int g = 0; g < 3; g++){
    const uint4* p = (const uint4*)(a.Whh + ((size_t)(g * H_ + i)) * H_ + kg * 32);
    #pragma unroll
    for (int q = 0; q < 4; q++) Wv[g][q] = p[q];
  }

  float ho = 0.f, xr0 = 0.f, xz0 = 0.f, xn0 = 0.f, bh0 = 0.f, bh1 = 0.f, bh2 = 0.f;
  if (tid < 32){
    bh0 = bf2f(a.bhh[ibase + tid]);
    bh1 = bf2f(a.bhh[H_ + ibase + tid]);
    bh2 = bf2f(a.bhh[2 * H_ + ibase + tid]);
    size_t base = ((size_t)(b * S_)) * 3072 + ibase + tid;
    xr0 = a.xg[base]; xz0 = a.xg[base + 1024]; xn0 = a.xg[base + 2048];
  }

  for (int t = 0; t < S_; t++){
    const int p = t & 1;
    if (tid < 512){
      const u64* rp = (const u64*)(a.hslot + ((size_t)((p ^ 1) * B_ + b)) * H_) + tid;
      const u32 tg = (u32)t;
      u64 u0;
      do {
        u0 = __hip_atomic_load(rp, __ATOMIC_RELAXED, __HIP_MEMORY_SCOPE_AGENT);
      } while ((((u32)(u0 >> 16) & 0xffffu) != tg) | (((u32)(u0 >> 48)) != tg));
      lds_hpk[p][tid] = ((u32)u0 & 0xffffu) | (((u32)(u0 >> 32)) << 16);
    }
    __syncthreads();
    const u32* hp = &lds_hpk[p][kg * 16];
    float pr = 0.f, pz = 0.f, pn = 0.f;
    #pragma unroll
    for (int q = 0; q < 4; q++){
      uint4 wr = Wv[0][q], wz = Wv[1][q], wn4 = Wv[2][q];
      u32 cr[4] = {wr.x, wr.y, wr.z, wr.w};
      u32 cz[4] = {wz.x, wz.y, wz.z, wz.w};
      u32 cn[4] = {wn4.x, wn4.y, wn4.z, wn4.w};
      #pragma unroll
      for (int e = 0; e < 4; e++){
        u32 h2 = hp[q * 4 + e];
        pr = dot2f16(cr[e], h2, pr);
        pz = dot2f16(cz[e], h2, pz);
        pn = dot2f16(cn[e], h2, pn);
      }
    }
    pr += __shfl_xor(pr, 32, 64);
    pz += __shfl_xor(pz, 32, 64);
    pn += __shfl_xor(pn, 32, 64);
    if ((tid & 63) < 32){
      red[0][w][il] = pr; red[1][w][il] = pz; red[2][w][il] = pn;
    }
    __syncthreads();
    if (tid < 32){
      __builtin_amdgcn_s_setprio(1);
      float hr = 0.f, hz = 0.f, hn = 0.f;
      #pragma unroll
      for (int ww = 0; ww < 16; ww++){
        hr += red[0][ww][tid]; hz += red[1][ww][tid]; hn += red[2][ww][tid];
      }
      float r = sigm(xr0 + hr + bh0);
      float z = sigm(xz0 + hz + bh1);
      float xx = xn0 + r * (hn + bh2);
      float ax = fabsf(xx);
      float et = __expf(-2.f * ax);                     // overflow-safe fast tanh
      float n = copysignf((1.f - et) * __builtin_amdgcn_rcpf(1.f + et), xx);
      float hnew = (1.f - z) * n + z * ho;
      ho = hnew;
      u16 h16 = __builtin_bit_cast(u16, (_Float16)hnew);
      u32 tgv = (((u32)(t + 1)) << 16) | (u32)h16;
      __hip_atomic_store(&a.hslot[((size_t)(p * B_ + b)) * H_ + ibase + tid], tgv,
                         __ATOMIC_RELAXED, __HIP_MEMORY_SCOPE_AGENT);
      __builtin_amdgcn_s_setprio(0);
      a.states[((size_t)(b * S_ + t)) * H_ + ibase + tid] = f2bf(hnew);
      // progress publish: chunk of 128 steps done for this WG's 32 columns.
      // release orders (drains) the wave's prior states stores.
      if (((t + 1) & 127) == 0 && tid == 0)
        __hip_atomic_fetch_add(&a.ctr[b * 8 + (t >> 7)], 1u,
                               __ATOMIC_RELEASE, __HIP_MEMORY_SCOPE_AGENT);
      if (t + 1 < S_){
        size_t base = ((size_t)(b * S_ + t + 1)) * 3072 + ibase + tid;
        xr0 = a.xg[base]; xz0 = a.xg[base + 1024]; xn0 = a.xg[base + 2048];
      }
    }
  }
}

// ---------------- g gate: sigmoid(states @ Wg + bg) ----------------
__global__ __launch_bounds__(256) void gk_kernel(const u16* __restrict__ states,
    const u16* __restrict__ Wg, const u16* __restrict__ bg, float* __restrict__ gws)
{
  int row = blockIdx.x * 4 + (threadIdx.x >> 6);
  int lane = threadIdx.x & 63;
  const u16* sr = states + (size_t)row * H_;
  float p = 0.f;
  #pragma unroll
  for (int j = 0; j < 16; j++){
    int c = j * 64 + lane;
    p += bf2f(sr[c]) * bf2f(Wg[c]);
  }
  #pragma unroll
  for (int o = 32; o; o >>= 1) p += __shfl_xor(p, o, 64);
  if (lane == 0) gws[row] = sigm(p + bf2f(bg[0]));
}

// ---------------- fused attention + scatter (post-mega; adds onto final logits) ----------------
__global__ __launch_bounds__(256) void attn_scatter_kernel(
    const float* __restrict__ scores, const float* __restrict__ gws,
    const float* __restrict__ scal, const int* __restrict__ sorted,
    float* __restrict__ out)
{
  int s = blockIdx.x, b = blockIdx.y;
  if (s == 0) return;
  int tid = threadIdx.x;
  __shared__ float grow[S_];
  __shared__ int   sb[S_];
  __shared__ float rbm[4], rbs[4];
  const float* srow = scores + ((size_t)(b * S_ + s)) * S_;
  #pragma unroll
  for (int r = 0; r < 4; r++) sb[tid + 256 * r] = sorted[b * S_ + tid + 256 * r];
  float myS[4];
  float lmax = -1e30f;
  #pragma unroll
  for (int r = 0; r < 4; r++){
    int t = tid + 256 * r;
    if (t < s){
      float d = srow[t] * 0.0625f;       // 1/sqrt(256)
      myS[r] = d;
      lmax = fmaxf(lmax, d);
    }
  }
  #pragma unroll
  for (int o = 32; o; o >>= 1) lmax = fmaxf(lmax, __shfl_xor(lmax, o, 64));
  if ((tid & 63) == 0) rbm[tid >> 6] = lmax;
  __syncthreads();
  float gmax = fmaxf(fmaxf(rbm[0], rbm[1]), fmaxf(rbm[2], rbm[3]));
  float lsum = 0.f;
  #pragma unroll
  for (int r = 0; r < 4; r++){
    int t = tid + 256 * r;
    if (t < s){ myS[r] = __expf(myS[r] - gmax); lsum += myS[r]; }
  }
  #pragma unroll
  for (int o = 32; o; o >>= 1) lsum += __shfl_xor(lsum, o, 64);
  if ((tid & 63) == 0) rbs[tid >> 6] = lsum;
  __syncthreads();
  float gsum = rbs[0] + rbs[1] + rbs[2] + rbs[3];
  float fac = gws[b * S_ + s] * scal[1] / gsum;
  #pragma unroll
  for (int r = 0; r < 4; r++){
    int t = tid + 256 * r;
    if (t < s) grow[t] = myS[r] * fac;
  }
  __syncthreads();
  float* orow = out + ((size_t)(b * S_ + s)) * V_;
  #pragma unroll
  for (int r = 0; r < 4; r++){
    int e = tid + 256 * r;
    int pk = sb[e];
    int v = pk >> 11;
    if (e > 0 && (sb[e - 1] >> 11) == v) continue;   // only leaders
    float sum = 0.f; bool any = false;
    for (int j = e; j < S_; j++){
      int pj = sb[j];
      if ((pj >> 11) != v) break;
      int t = pj & 2047;
      if (t < s){ sum += grow[t]; any = true; }
    }
    if (any) orow[v] += sum;
  }
}

extern "C" void kernel_launch(void* const* d_in, const int* in_sizes, int n_in,
                              void* d_out, int out_size, void* d_ws, size_t ws_size,
                              hipStream_t stream)
{
  const int*  ids   = (const int*)d_in[0];
  const void* emb   = d_in[1];
  const void* W_ih  = d_in[2];
  const void* W_hh  = d_in[3];
  const void* b_ih  = d_in[4];
  const void* b_hh  = d_in[5];
  const void* Wq    = d_in[6];
  const void* bq    = d_in[7];
  const void* Wk    = d_in[8];
  const void* bk    = d_in[9];
  const void* Wg    = d_in[10];
  const void* bg    = d_in[11];
  const void* Whe   = d_in[12];
  const void* bhe   = d_in[13];
  const void* obias = d_in[14];
  const void* ms    = d_in[15];
  const void* smW   = d_in[16];
  const void* lam   = d_in[17];
  (void)in_sizes; (void)n_in; (void)out_size; (void)ws_size;

  char* ws = (char*)d_ws;
  int*   flag   = (int*)(ws + 0);
  float* scal   = (float*)(ws + 256);
  u32*   hslot  = (u32*)(ws + 512);        // [2][B][H] tagged-f16 u32 slots (16 KB)
  u16*   zbias  = (u16*)(ws + 16896);      // 2 KB of bf16 zeros
  u32*   ctr    = (u32*)(ws + 20480);      // sync counters (33 u32, memset 256 B)
  u16*   c_emb  = (u16*)(ws + 33280);
  u16*   c_Wih  = (u16*)(ws + 32801280);
  u16*   c_Whh  = (u16*)(ws + 35947008);   // f16 content (GRU dot2 path)
  u16*   c_Wq   = (u16*)(ws + 42238464);
  u16*   c_Wk   = (u16*)(ws + 42762752);
  u16*   c_Wg   = (u16*)(ws + 43287040);
  u16*   c_Whe  = (u16*)(ws + 43289088);
  u16*   c_bih  = (u16*)(ws + 44337664);
  u16*   c_bhh  = (u16*)(ws + 44343808);
  u16*   c_bq   = (u16*)(ws + 44349952);
  u16*   c_bk   = (u16*)(ws + 44350464);
  u16*   c_bg   = (u16*)(ws + 44350976);
  u16*   c_bhe  = (u16*)(ws + 44351232);
  u16*   c_ob   = (u16*)(ws + 44352256);
  u16*   c_smW  = (u16*)(ws + 44416512);
  u16*   xs     = (u16*)(ws + 44416768);
  float* xg     = (float*)(ws + 46513920);
  u16*   states = (u16*)(ws + 71679744);
  u16*   hs     = (u16*)(ws + 75874048);
  u16*   qb     = (u16*)(ws + 77971200);
  u16*   kb     = (u16*)(ws + 79019776);
  float* gws    = (float*)(ws + 80068352);
  int*   sorted = (int*)(ws + 88465152);
  float* scores = xg;                      // xg region dead for b=0 rows only after gru;
                                           // scores written post-qkv (== post-gru) — safe
  float* out = (float*)d_out;

  hipMemsetAsync(hslot, 0, 16384, stream);   // h0 = 0 with tag 0
  hipMemsetAsync(zbias, 0, 2048, stream);    // zero bias for scores GEMM
  hipMemsetAsync(ctr, 0, 256, stream);       // progress / done counters
  detect_kernel<<<dim3(1), dim3(64), 0, stream>>>((const u32*)emb, flag, scal, lam, ms);

  ConvArgs ca;
  ca.s[0] = emb;  ca.s[1] = W_ih; ca.s[2] = W_hh; ca.s[3] = Wq;   ca.s[4] = Wk;
  ca.s[5] = Wg;   ca.s[6] = Whe;  ca.s[7] = b_ih; ca.s[8] = b_hh; ca.s[9] = bq;
  ca.s[10] = bk;  ca.s[11] = bg;  ca.s[12] = bhe; ca.s[13] = obias; ca.s[14] = smW;
  convall_kernel<<<dim3((CONV_TOTAL + 255) / 256), dim3(256), 0, stream>>>(ca, ws, flag);

  smear_kernel<<<dim3(B_ * S_), dim3(64), 0, stream>>>(ids, c_emb, c_smW, scal, xs);
  gemm_bt<false><<<dim3(3072 / 128, 2048 / 128), dim3(256), 0, stream>>>(xs, c_Wih, c_bih, (void*)xg, E_, 3072);

  MegaArgs ma;
  ma.xg = xg;        ma.Whh = c_Whh;  ma.bhh = c_bhh;  ma.hslot = hslot;  ma.states = states;
  ma.ids = ids;      ma.sorted = sorted;
  ma.Whe = c_Whe;    ma.bhe = c_bhe;  ma.hs = hs;
  ma.Wq = c_Wq;      ma.bq = c_bq;    ma.qb = qb;
  ma.Wk = c_Wk;      ma.bk = c_bk;    ma.kb = kb;
  ma.emb = c_emb;    ma.ob = c_ob;    ma.out = out;
  ma.zbias = zbias;  ma.scores = scores;
  ma.ctr = ctr;
  mega_kernel<<<dim3(256), dim3(1024), 0, stream>>>(ma);

  gk_kernel<<<dim3(512), dim3(256), 0, stream>>>(states, c_Wg, c_bg, gws);
  attn_scatter_kernel<<<dim3(S_, B_), dim3(256), 0, stream>>>(scores, gws, scal, sorted, out);
}

// Round 14
// 3220.157 us; speedup vs baseline: 1.4660x; 1.4660x over previous
//
#include <hip/hip_runtime.h>
#include <stdint.h>

#define V_ 32000
#define E_ 512
#define H_ 1024
#define M_ 256
#define B_ 2
#define S_ 1024
#define GC_ 24

typedef unsigned short u16;
typedef unsigned int u32;
typedef unsigned long long u64;

typedef __attribute__((ext_vector_type(8))) short short8;
typedef __attribute__((ext_vector_type(4))) float floatx4;
typedef __attribute__((ext_vector_type(2))) float floatx2;
typedef __attribute__((ext_vector_type(2))) _Float16 halfx2;

__device__ __forceinline__ float bf2f(u16 u){ return __uint_as_float(((u32)u) << 16); }
__device__ __forceinline__ float bflo(u32 u){ return __uint_as_float(u << 16); }
__device__ __forceinline__ float bfhi(u32 u){ return __uint_as_float(u & 0xffff0000u); }
__device__ __forceinline__ u16 f2bf(float f){
  u32 u = __float_as_uint(f);
  u32 r = (u + 0x7fffu + ((u >> 16) & 1u)) >> 16;
  return (u16)r;
}
__device__ __forceinline__ float sigm(float x){ return 1.f / (1.f + __expf(-x)); }

// 2-wide f16 dot product accumulating into f32 (v_dot2_f32_f16); graceful fallback.
__device__ __forceinline__ float dot2f16(u32 a, u32 b, float c){
#if __has_builtin(__builtin_amdgcn_fdot2)
  return __builtin_amdgcn_fdot2(__builtin_bit_cast(halfx2, a),
                                __builtin_bit_cast(halfx2, b), c, false);
#else
  halfx2 av = __builtin_bit_cast(halfx2, a);
  halfx2 bv = __builtin_bit_cast(halfx2, b);
  return fmaf((float)av.y, (float)bv.y, fmaf((float)av.x, (float)bv.x, c));
#endif
}

// async global->LDS 16B (wave-uniform LDS base + lane*16 scatter; per-lane global src)
__device__ __forceinline__ void gload_lds16(const void* g, void* l){
  __builtin_amdgcn_global_load_lds(
      (const __attribute__((address_space(1))) void*)g,
      (__attribute__((address_space(3))) void*)l, 16, 0, 0);
}

// ---------------- dtype probe: low-u16-as-bf16 plausibility test on emb ----------------
__global__ __launch_bounds__(64) void detect_kernel(const u32* __restrict__ emb,
    int* __restrict__ flag, float* __restrict__ scal,
    const void* __restrict__ lam, const void* __restrict__ ms)
{
  int lane = threadIdx.x;
  int c = 0;
  for (int i = lane; i < 256; i += 64){
    u32 w = emb[i];
    float a = fabsf(__uint_as_float((w & 0xffffu) << 16));
    if (a > 1e-5f && a < 1.0f) c++;
  }
  #pragma unroll
  for (int o = 32; o; o >>= 1) c += __shfl_down(c, o, 64);
  if (lane == 0){
    int isf32 = (c < 128) ? 1 : 0;
    *flag = isf32;
    if (isf32) scal[0] = ((const float*)lam)[0];
    else {
      float v = bf2f(((const u16*)lam)[0]);
      scal[0] = (fabsf(v) <= 4.0f) ? v : ((const float*)lam)[0];
    }
    if (isf32) scal[1] = ((const float*)ms)[0];
    else {
      u16 a = ((const u16*)ms)[0];
      float v = bf2f(a);
      scal[1] = (a != 0 && fabsf(v) > 1e-4f && fabsf(v) < 1e4f) ? v : ((const float*)ms)[0];
    }
  }
}

// ---------------- merged canonicalization: all 15 tensors in ONE launch ----------------
struct ConvArgs { const void* s[15]; };

#define CONV_TOTAL 22191385
__global__ __launch_bounds__(256) void convall_kernel(ConvArgs a, char* __restrict__ ws,
                                                      const int* __restrict__ flag)
{
  static const int    ns[15]    = {16384000, 1572864, 3145728, 262144, 262144, 1024,
                                   524288, 3072, 3072, 256, 256, 1, 512, 32000, 24};
  static const size_t doffs[15] = {33280, 32801280, 35947008, 42238464, 42762752,
                                   43287040, 43289088, 44337664, 44343808, 44349952,
                                   44350464, 44350976, 44351232, 44352256, 44416512};
  int gid = blockIdx.x * 256 + threadIdx.x;
  if (gid >= CONV_TOTAL) return;
  int isf32 = *flag;
  int seg = -1, r = gid;
  #pragma unroll
  for (int k = 0; k < 15; k++){
    if (seg < 0){ if (r < ns[k]) seg = k; else r -= ns[k]; }
  }
  const void* src = a.s[seg];
  u16* dst = (u16*)(ws + doffs[seg]);
  if (seg == 2){   // W_hh -> f16 (GRU dot2 path)
    float v = isf32 ? ((const float*)src)[r] : bf2f(((const u16*)src)[r]);
    dst[r] = __builtin_bit_cast(u16, (_Float16)v);
  } else {         // bf16 canonical
    dst[r] = isf32 ? f2bf(((const float*)src)[r]) : ((const u16*)src)[r];
  }
}

// ---------------- smear: x' = emb[ids]; x'[t] += lam*sigmoid(x[t,:24]@smW)*x[t-1] ----------------
__global__ __launch_bounds__(64) void smear_kernel(const int* __restrict__ ids,
    const u16* __restrict__ emb, const u16* __restrict__ smW,
    const float* __restrict__ scal, u16* __restrict__ xs)
{
  int row = blockIdx.x;                 // b*S + t
  int t = row & (S_ - 1);
  int lane = threadIdx.x;
  int id = ids[row];
  const u16* er = emb + (size_t)id * E_;
  float sg = 0.f;
  if (t > 0){
    float p = 0.f;
    if (lane < GC_) p = bf2f(er[lane]) * bf2f(smW[lane]);
    #pragma unroll
    for (int o = 32; o; o >>= 1) p += __shfl_down(p, o, 64);
    float dot = __shfl(p, 0, 64);
    sg = scal[0] * sigm(dot);
  }
  uint4 cur = ((const uint4*)er)[lane];
  uint4 outv = cur;
  if (t > 0){
    const u16* ep = emb + (size_t)ids[row - 1] * E_;
    uint4 prv = ((const uint4*)ep)[lane];
    const u16* cu = (const u16*)&cur;
    const u16* pu = (const u16*)&prv;
    u16* po = (u16*)&outv;
    #pragma unroll
    for (int j = 0; j < 8; j++) po[j] = f2bf(bf2f(cu[j]) + sg * bf2f(pu[j]));
  }
  ((uint4*)(xs + (size_t)row * E_))[lane] = outv;
}

// ---------------- generic MFMA GEMM kernel (used for the pre-GRU xg GEMM) ----------------
template<bool OUT_BF16>
__global__ __launch_bounds__(256) void gemm_bt(
    const u16* __restrict__ A, const u16* __restrict__ Bm,
    const u16* __restrict__ bias, void* __restrict__ Cout,
    int K, int Ndim)
{
  int wave = threadIdx.x >> 6, lane = threadIdx.x & 63;
  int wm = wave >> 1, wn = wave & 1;
  int m0 = blockIdx.y * 128 + wm * 64;
  int n0 = blockIdx.x * 128 + wn * 64;
  int lrow = lane & 15, lq = lane >> 4;
  floatx4 acc[4][4];
  #pragma unroll
  for (int i = 0; i < 4; i++)
    #pragma unroll
    for (int j = 0; j < 4; j++) acc[i][j] = (floatx4)0.f;
  const u16* Ab = A + (size_t)(m0 + lrow) * K + lq * 8;
  const u16* Bb = Bm + (size_t)(n0 + lrow) * K + lq * 8;
  for (int k0 = 0; k0 < K; k0 += 32){
    short8 af[4], bfr[4];
    #pragma unroll
    for (int tt = 0; tt < 4; tt++)
      af[tt] = *(const short8*)(Ab + (size_t)tt * 16 * K + k0);
    #pragma unroll
    for (int tt = 0; tt < 4; tt++)
      bfr[tt] = *(const short8*)(Bb + (size_t)tt * 16 * K + k0);
    #pragma unroll
    for (int im = 0; im < 4; im++)
      #pragma unroll
      for (int in = 0; in < 4; in++)
        acc[im][in] = __builtin_amdgcn_mfma_f32_16x16x32_bf16(af[im], bfr[in], acc[im][in], 0, 0, 0);
  }
  #pragma unroll
  for (int in = 0; in < 4; in++){
    int n = n0 + in * 16 + lrow;
    float bv = bf2f(bias[n]);
    #pragma unroll
    for (int im = 0; im < 4; im++){
      int mb = m0 + im * 16 + lq * 4;
      #pragma unroll
      for (int r = 0; r < 4; r++){
        float v = acc[im][in][r] + bv;
        size_t off = (size_t)(mb + r) * Ndim + n;
        if (OUT_BF16) ((u16*)Cout)[off] = f2bf(v);
        else          ((float*)Cout)[off] = v;
      }
    }
  }
}

// ---------------- device-side 128x128 GEMM tile (gemm_bt body, callable by workers) ----------------
__device__ void tile_gemm(const u16* __restrict__ A, const u16* __restrict__ Bm,
                          const u16* __restrict__ bias, void* __restrict__ Cout,
                          int K, int Ndim, int tm0, int tn0, int wave, int lane, int outbf)
{
  int wm = wave >> 1, wn = wave & 1;
  int m0 = tm0 + wm * 64;
  int n0 = tn0 + wn * 64;
  int lrow = lane & 15, lq = lane >> 4;
  floatx4 acc[4][4];
  #pragma unroll
  for (int i = 0; i < 4; i++)
    #pragma unroll
    for (int j = 0; j < 4; j++) acc[i][j] = (floatx4)0.f;
  const u16* Ab = A + (size_t)(m0 + lrow) * K + lq * 8;
  const u16* Bb = Bm + (size_t)(n0 + lrow) * K + lq * 8;
  for (int k0 = 0; k0 < K; k0 += 32){
    short8 af[4], bfr[4];
    #pragma unroll
    for (int tt = 0; tt < 4; tt++)
      af[tt] = *(const short8*)(Ab + (size_t)tt * 16 * K + k0);
    #pragma unroll
    for (int tt = 0; tt < 4; tt++)
      bfr[tt] = *(const short8*)(Bb + (size_t)tt * 16 * K + k0);
    #pragma unroll
    for (int im = 0; im < 4; im++)
      #pragma unroll
      for (int in = 0; in < 4; in++)
        acc[im][in] = __builtin_amdgcn_mfma_f32_16x16x32_bf16(af[im], bfr[in], acc[im][in], 0, 0, 0);
  }
  #pragma unroll
  for (int in = 0; in < 4; in++){
    int n = n0 + in * 16 + lrow;
    float bv = bf2f(bias[n]);
    #pragma unroll
    for (int im = 0; im < 4; im++){
      int mb = m0 + im * 16 + lq * 4;
      #pragma unroll
      for (int r = 0; r < 4; r++){
        float v = acc[im][in][r] + bv;
        size_t off = (size_t)(mb + r) * Ndim + n;
        if (outbf) ((u16*)Cout)[off] = f2bf(v);
        else       ((float*)Cout)[off] = v;
      }
    }
  }
}

// ---------------- LDS-staged MFMA GEMM (transposed block map) for the big V-GEMM ----------------
// Stays a POST-kernel: its 295+ MB of streaming traffic evicted the GRU mailboxes
// when run in-shadow (v14, 2.4x gru slowdown). M-tile <- blockIdx.x (16), N-tile <-
// blockIdx.y (250): 16 consecutive blocks share one emb B-tile -> emb read once.
__global__ __launch_bounds__(256) void gemm_v(
    const u16* __restrict__ A, const u16* __restrict__ Bm,
    const u16* __restrict__ bias, float* __restrict__ Cout,
    int K, int Ndim)
{
  __shared__ u16 la[128 * 32];
  __shared__ u16 lb[128 * 32];
  int wave = threadIdx.x >> 6, lane = threadIdx.x & 63;
  int wm = wave >> 1, wn = wave & 1;
  int tm0 = blockIdx.x * 128, tn0 = blockIdx.y * 128;
  int m0 = tm0 + wm * 64;
  int n0 = tn0 + wn * 64;
  int lrow = lane & 15, lq = lane >> 4;
  floatx4 acc[4][4];
  #pragma unroll
  for (int i = 0; i < 4; i++)
    #pragma unroll
    for (int j = 0; j < 4; j++) acc[i][j] = (floatx4)0.f;

  const int o = wave * 1024 + lane * 16;
  for (int k0 = 0; k0 < K; k0 += 32){
    #pragma unroll
    for (int j = 0; j < 2; j++){
      int oo = o + j * 4096;
      int row = oo >> 6;
      int ce  = (oo & 63) >> 1;
      gload_lds16(&A[(size_t)(tm0 + row) * K + k0 + ce],  &la[(wave * 1024 + j * 4096) >> 1]);
      gload_lds16(&Bm[(size_t)(tn0 + row) * K + k0 + ce], &lb[(wave * 1024 + j * 4096) >> 1]);
    }
    __syncthreads();
    short8 af[4], bfr[4];
    #pragma unroll
    for (int tt = 0; tt < 4; tt++)
      af[tt] = *(const short8*)&la[(wm * 64 + tt * 16 + lrow) * 32 + lq * 8];
    #pragma unroll
    for (int tt = 0; tt < 4; tt++)
      bfr[tt] = *(const short8*)&lb[(wn * 64 + tt * 16 + lrow) * 32 + lq * 8];
    #pragma unroll
    for (int im = 0; im < 4; im++)
      #pragma unroll
      for (int in = 0; in < 4; in++)
        acc[im][in] = __builtin_amdgcn_mfma_f32_16x16x32_bf16(af[im], bfr[in], acc[im][in], 0, 0, 0);
    __syncthreads();
  }
  #pragma unroll
  for (int in = 0; in < 4; in++){
    int n = n0 + in * 16 + lrow;
    float bv = bf2f(bias[n]);
    #pragma unroll
    for (int im = 0; im < 4; im++){
      int mb = m0 + im * 16 + lq * 4;
      #pragma unroll
      for (int r = 0; r < 4; r++)
        Cout[(size_t)(mb + r) * Ndim + n] = acc[im][in][r] + bv;
    }
  }
}

// ---------------- mega-kernel: gru (0-63) + sort (64-65) + LIGHT shadow workers (66+) ----------------
// v15 = v14 minus the streamers: workers handle only hs/qkv (chunk-gated), gk
// (chunk-gated), and scores (gated on all qkv) — ~25 MB total traffic, so the
// hslot mailboxes stay L3-hot (v14's failure mode). 80 quads, one per worker WG;
// workers 80+ exit immediately. V-GEMM + attn_scatter remain post-kernels.
struct MegaArgs {
  const float* xg; const u16* Whh; const u16* bhh; u32* hslot; u16* states;
  const int* ids; int* sorted;
  const u16* Whe; const u16* bhe; u16* hs;
  const u16* Wq;  const u16* bq;  u16* qb;
  const u16* Wk;  const u16* bk;  u16* kb;
  const u16* Wg;  const u16* bg;  float* gws;
  const u16* zbias; float* scores;
  u32* ctr;   // [0..15] prog (b*8+chunk, target 32), [32] qkv_total (target 16)
};

__global__ __launch_bounds__(1024) void mega_kernel(MegaArgs a)
{
  const int tid = threadIdx.x;

  // ---------------- sort WGs ----------------
  __shared__ int arr[S_];
  if (blockIdx.x >= 64 && blockIdx.x < 66){
    int b = blockIdx.x - 64;
    arr[tid] = (a.ids[b * S_ + tid] << 11) | tid;
    __syncthreads();
    for (int k = 2; k <= S_; k <<= 1){
      for (int j = k >> 1; j > 0; j >>= 1){
        int ixj = tid ^ j;
        if (ixj > tid){
          int x = arr[tid], c = arr[ixj];
          bool dir = (tid & k) == 0;
          if (dir ? (x > c) : (x < c)){ arr[tid] = c; arr[ixj] = x; }
        }
        __syncthreads();
      }
    }
    a.sorted[b * S_ + tid] = arr[tid];
    return;
  }

  // ---------------- light shadow workers ----------------
  if (blockIdx.x >= 66){
    const int wid = blockIdx.x - 66;
    if (wid >= 80) return;                 // 80 quads, one per WG
    const int qt = tid >> 8;               // quarter 0..3
    const int qtid = tid & 255;
    const int wave = qtid >> 6, lane = qtid & 63;
    u32* prog = a.ctr;
    u32* qkvt = a.ctr + 32;
    int q = wid;
    int type, mt = 0, sbb = 0, si = 0, sj0 = 0;
    if (q < 48){
      int c = q / 6, r = q - c * 6;        // chunk-major: {hs b0,b1, qkv b0,b1, gk b0,b1}
      type = r >> 1;                       // 0=hs, 1=qkv, 2=gk
      mt = c + 8 * (r & 1);                // m-tile == prog index (b*8+chunk)
    } else {
      type = 3; int r = q - 48; sbb = r >> 4;
      int qq = r & 15; si = qq >> 1; sj0 = (qq & 1) * 4;
    }
    if (tid == 0){
      if (type <= 2){
        while (__hip_atomic_load(&prog[mt], __ATOMIC_ACQUIRE, __HIP_MEMORY_SCOPE_AGENT) < 32u)
          __builtin_amdgcn_s_sleep(8);
      } else {
        while (__hip_atomic_load(qkvt, __ATOMIC_ACQUIRE, __HIP_MEMORY_SCOPE_AGENT) < 16u)
          __builtin_amdgcn_s_sleep(8);
      }
    }
    __syncthreads();
    if (type == 0){
      tile_gemm(a.states, a.Whe, a.bhe, a.hs, H_, 512, mt * 128, qt * 128, wave, lane, 1);
    } else if (type == 1){
      if (qt < 2) tile_gemm(a.states, a.Wq, a.bq, a.qb, H_, M_, mt * 128, qt * 128, wave, lane, 1);
      else        tile_gemm(a.states, a.Wk, a.bk, a.kb, H_, M_, mt * 128, (qt - 2) * 128, wave, lane, 1);
    } else if (type == 2){
      // gk: rows [mt*128, mt*128+128); 8 lanes x 128 contiguous cols each
      int r = tid >> 3, l8 = tid & 7;
      int row = mt * 128 + r;
      const u16* sr = a.states + (size_t)row * H_ + l8 * 128;
      const u16* wgp = a.Wg + l8 * 128;
      float p = 0.f;
      #pragma unroll
      for (int j = 0; j < 16; j++){
        uint4 sv = ((const uint4*)sr)[j];
        uint4 wv = ((const uint4*)wgp)[j];
        u32 ss[4] = {sv.x, sv.y, sv.z, sv.w};
        u32 ww[4] = {wv.x, wv.y, wv.z, wv.w};
        #pragma unroll
        for (int e = 0; e < 4; e++)
          p += bflo(ss[e]) * bflo(ww[e]) + bfhi(ss[e]) * bfhi(ww[e]);
      }
      p += __shfl_xor(p, 1, 64);
      p += __shfl_xor(p, 2, 64);
      p += __shfl_xor(p, 4, 64);
      if (l8 == 0) a.gws[row] = sigm(p + bf2f(a.bg[0]));
    } else {
      int j = sj0 + qt;
      tile_gemm(a.qb + (size_t)sbb * S_ * M_, a.kb + (size_t)sbb * S_ * M_, a.zbias,
                a.scores + (size_t)sbb * S_ * S_, M_, S_, si * 128, j * 128, wave, lane, 0);
    }
    __syncthreads();   // drains all waves' stores before the release post
    if (tid == 0 && type == 1)
      __hip_atomic_fetch_add(qkvt, 1u, __ATOMIC_RELEASE, __HIP_MEMORY_SCOPE_AGENT);
    return;
  }

  // ---------------- gru WGs (v10 math + per-128-step progress publish) ----------------
  const int b = blockIdx.x >> 5;
  const int ibase = (blockIdx.x & 31) * 32;
  const int kg = tid >> 5;
  const int il = tid & 31;
  const int i = ibase + il;
  const int w = tid >> 6;

  __shared__ u32   lds_hpk[2][H_ / 2];
  __shared__ float red[3][16][32];

  uint4 Wv[3][4];
  #pragma unroll
  for (int g = 0; g < 3; g++){
    const uint4* p = (const uint4*)(a.Whh + ((size_t)(g * H_ + i)) * H_ + kg * 32);
    #pragma unroll
    for (int q = 0; q < 4; q++) Wv[g][q] = p[q];
  }

  float ho = 0.f, xr0 = 0.f, xz0 = 0.f, xn0 = 0.f, bh0 = 0.f, bh1 = 0.f, bh2 = 0.f;
  if (tid < 32){
    bh0 = bf2f(a.bhh[ibase + tid]);
    bh1 = bf2f(a.bhh[H_ + ibase + tid]);
    bh2 = bf2f(a.bhh[2 * H_ + ibase + tid]);
    size_t base = ((size_t)(b * S_)) * 3072 + ibase + tid;
    xr0 = a.xg[base]; xz0 = a.xg[base + 1024]; xn0 = a.xg[base + 2048];
  }

  for (int t = 0; t < S_; t++){
    const int p = t & 1;
    if (tid < 512){
      const u64* rp = (const u64*)(a.hslot + ((size_t)((p ^ 1) * B_ + b)) * H_) + tid;
      const u32 tg = (u32)t;
      u64 u0;
      do {
        u0 = __hip_atomic_load(rp, __ATOMIC_RELAXED, __HIP_MEMORY_SCOPE_AGENT);
      } while ((((u32)(u0 >> 16) & 0xffffu) != tg) | (((u32)(u0 >> 48)) != tg));
      lds_hpk[p][tid] = ((u32)u0 & 0xffffu) | (((u32)(u0 >> 32)) << 16);
    }
    __syncthreads();
    const u32* hp = &lds_hpk[p][kg * 16];
    float pr = 0.f, pz = 0.f, pn = 0.f;
    #pragma unroll
    for (int q = 0; q < 4; q++){
      uint4 wr = Wv[0][q], wz = Wv[1][q], wn4 = Wv[2][q];
      u32 cr[4] = {wr.x, wr.y, wr.z, wr.w};
      u32 cz[4] = {wz.x, wz.y, wz.z, wz.w};
      u32 cn[4] = {wn4.x, wn4.y, wn4.z, wn4.w};
      #pragma unroll
      for (int e = 0; e < 4; e++){
        u32 h2 = hp[q * 4 + e];
        pr = dot2f16(cr[e], h2, pr);
        pz = dot2f16(cz[e], h2, pz);
        pn = dot2f16(cn[e], h2, pn);
      }
    }
    pr += __shfl_xor(pr, 32, 64);
    pz += __shfl_xor(pz, 32, 64);
    pn += __shfl_xor(pn, 32, 64);
    if ((tid & 63) < 32){
      red[0][w][il] = pr; red[1][w][il] = pz; red[2][w][il] = pn;
    }
    __syncthreads();
    if (tid < 32){
      __builtin_amdgcn_s_setprio(1);
      float hr = 0.f, hz = 0.f, hn = 0.f;
      #pragma unroll
      for (int ww = 0; ww < 16; ww++){
        hr += red[0][ww][tid]; hz += red[1][ww][tid]; hn += red[2][ww][tid];
      }
      float r = sigm(xr0 + hr + bh0);
      float z = sigm(xz0 + hz + bh1);
      float xx = xn0 + r * (hn + bh2);
      float ax = fabsf(xx);
      float et = __expf(-2.f * ax);                     // overflow-safe fast tanh
      float n = copysignf((1.f - et) * __builtin_amdgcn_rcpf(1.f + et), xx);
      float hnew = (1.f - z) * n + z * ho;
      ho = hnew;
      u16 h16 = __builtin_bit_cast(u16, (_Float16)hnew);
      u32 tgv = (((u32)(t + 1)) << 16) | (u32)h16;
      __hip_atomic_store(&a.hslot[((size_t)(p * B_ + b)) * H_ + ibase + tid], tgv,
                         __ATOMIC_RELAXED, __HIP_MEMORY_SCOPE_AGENT);
      __builtin_amdgcn_s_setprio(0);
      a.states[((size_t)(b * S_ + t)) * H_ + ibase + tid] = f2bf(hnew);
      if (((t + 1) & 127) == 0 && tid == 0)
        __hip_atomic_fetch_add(&a.ctr[b * 8 + (t >> 7)], 1u,
                               __ATOMIC_RELEASE, __HIP_MEMORY_SCOPE_AGENT);
      if (t + 1 < S_){
        size_t base = ((size_t)(b * S_ + t + 1)) * 3072 + ibase + tid;
        xr0 = a.xg[base]; xz0 = a.xg[base + 1024]; xn0 = a.xg[base + 2048];
      }
    }
  }
}

// ---------------- fused attention + scatter (post gemm_v; adds onto final logits) ----------------
__global__ __launch_bounds__(256) void attn_scatter_kernel(
    const float* __restrict__ scores, const float* __restrict__ gws,
    const float* __restrict__ scal, const int* __restrict__ sorted,
    float* __restrict__ out)
{
  int s = blockIdx.x, b = blockIdx.y;
  if (s == 0) return;
  int tid = threadIdx.x;
  __shared__ float grow[S_];
  __shared__ int   sb[S_];
  __shared__ float rbm[4], rbs[4];
  const float* srow = scores + ((size_t)(b * S_ + s)) * S_;
  #pragma unroll
  for (int r = 0; r < 4; r++) sb[tid + 256 * r] = sorted[b * S_ + tid + 256 * r];
  float myS[4];
  float lmax = -1e30f;
  #pragma unroll
  for (int r = 0; r < 4; r++){
    int t = tid + 256 * r;
    if (t < s){
      float d = srow[t] * 0.0625f;       // 1/sqrt(256)
      myS[r] = d;
      lmax = fmaxf(lmax, d);
    }
  }
  #pragma unroll
  for (int o = 32; o; o >>= 1) lmax = fmaxf(lmax, __shfl_xor(lmax, o, 64));
  if ((tid & 63) == 0) rbm[tid >> 6] = lmax;
  __syncthreads();
  float gmax = fmaxf(fmaxf(rbm[0], rbm[1]), fmaxf(rbm[2], rbm[3]));
  float lsum = 0.f;
  #pragma unroll
  for (int r = 0; r < 4; r++){
    int t = tid + 256 * r;
    if (t < s){ myS[r] = __expf(myS[r] - gmax); lsum += myS[r]; }
  }
  #pragma unroll
  for (int o = 32; o; o >>= 1) lsum += __shfl_xor(lsum, o, 64);
  if ((tid & 63) == 0) rbs[tid >> 6] = lsum;
  __syncthreads();
  float gsum = rbs[0] + rbs[1] + rbs[2] + rbs[3];
  float fac = gws[b * S_ + s] * scal[1] / gsum;
  #pragma unroll
  for (int r = 0; r < 4; r++){
    int t = tid + 256 * r;
    if (t < s) grow[t] = myS[r] * fac;
  }
  __syncthreads();
  float* orow = out + ((size_t)(b * S_ + s)) * V_;
  #pragma unroll
  for (int r = 0; r < 4; r++){
    int e = tid + 256 * r;
    int pk = sb[e];
    int v = pk >> 11;
    if (e > 0 && (sb[e - 1] >> 11) == v) continue;   // only leaders
    float sum = 0.f; bool any = false;
    for (int j = e; j < S_; j++){
      int pj = sb[j];
      if ((pj >> 11) != v) break;
      int t = pj & 2047;
      if (t < s){ sum += grow[t]; any = true; }
    }
    if (any) orow[v] += sum;
  }
}

extern "C" void kernel_launch(void* const* d_in, const int* in_sizes, int n_in,
                              void* d_out, int out_size, void* d_ws, size_t ws_size,
                              hipStream_t stream)
{
  const int*  ids   = (const int*)d_in[0];
  const void* emb   = d_in[1];
  const void* W_ih  = d_in[2];
  const void* W_hh  = d_in[3];
  const void* b_ih  = d_in[4];
  const void* b_hh  = d_in[5];
  const void* Wq    = d_in[6];
  const void* bq    = d_in[7];
  const void* Wk    = d_in[8];
  const void* bk    = d_in[9];
  const void* Wg    = d_in[10];
  const void* bg    = d_in[11];
  const void* Whe   = d_in[12];
  const void* bhe   = d_in[13];
  const void* obias = d_in[14];
  const void* ms    = d_in[15];
  const void* smW   = d_in[16];
  const void* lam   = d_in[17];
  (void)in_sizes; (void)n_in; (void)out_size; (void)ws_size;

  char* ws = (char*)d_ws;
  int*   flag   = (int*)(ws + 0);
  float* scal   = (float*)(ws + 256);
  u32*   hslot  = (u32*)(ws + 512);        // [2][B][H] tagged-f16 u32 slots (16 KB)
  u16*   zbias  = (u16*)(ws + 16896);      // 2 KB of bf16 zeros
  u32*   ctr    = (u32*)(ws + 20480);      // sync counters
  u16*   c_emb  = (u16*)(ws + 33280);
  u16*   c_Wih  = (u16*)(ws + 32801280);
  u16*   c_Whh  = (u16*)(ws + 35947008);   // f16 content (GRU dot2 path)
  u16*   c_Wq   = (u16*)(ws + 42238464);
  u16*   c_Wk   = (u16*)(ws + 42762752);
  u16*   c_Wg   = (u16*)(ws + 43287040);
  u16*   c_Whe  = (u16*)(ws + 43289088);
  u16*   c_bih  = (u16*)(ws + 44337664);
  u16*   c_bhh  = (u16*)(ws + 44343808);
  u16*   c_bq   = (u16*)(ws + 44349952);
  u16*   c_bk   = (u16*)(ws + 44350464);
  u16*   c_bg   = (u16*)(ws + 44350976);
  u16*   c_bhe  = (u16*)(ws + 44351232);
  u16*   c_ob   = (u16*)(ws + 44352256);
  u16*   c_smW  = (u16*)(ws + 44416512);
  u16*   xs     = (u16*)(ws + 44416768);
  float* xg     = (float*)(ws + 46513920);
  u16*   states = (u16*)(ws + 71679744);
  u16*   hs     = (u16*)(ws + 75874048);
  u16*   qb     = (u16*)(ws + 77971200);
  u16*   kb     = (u16*)(ws + 79019776);
  float* gws    = (float*)(ws + 80068352);
  int*   sorted = (int*)(ws + 88465152);
  float* scores = xg;                      // xg region dead once all qkv done (== gru done)
  float* out = (float*)d_out;

  hipMemsetAsync(hslot, 0, 16384, stream);   // h0 = 0 with tag 0
  hipMemsetAsync(zbias, 0, 2048, stream);    // zero bias for scores GEMM
  hipMemsetAsync(ctr, 0, 256, stream);       // progress / done counters
  detect_kernel<<<dim3(1), dim3(64), 0, stream>>>((const u32*)emb, flag, scal, lam, ms);

  ConvArgs ca;
  ca.s[0] = emb;  ca.s[1] = W_ih; ca.s[2] = W_hh; ca.s[3] = Wq;   ca.s[4] = Wk;
  ca.s[5] = Wg;   ca.s[6] = Whe;  ca.s[7] = b_ih; ca.s[8] = b_hh; ca.s[9] = bq;
  ca.s[10] = bk;  ca.s[11] = bg;  ca.s[12] = bhe; ca.s[13] = obias; ca.s[14] = smW;
  convall_kernel<<<dim3((CONV_TOTAL + 255) / 256), dim3(256), 0, stream>>>(ca, ws, flag);

  smear_kernel<<<dim3(B_ * S_), dim3(64), 0, stream>>>(ids, c_emb, c_smW, scal, xs);
  gemm_bt<false><<<dim3(3072 / 128, 2048 / 128), dim3(256), 0, stream>>>(xs, c_Wih, c_bih, (void*)xg, E_, 3072);

  MegaArgs ma;
  ma.xg = xg;        ma.Whh = c_Whh;  ma.bhh = c_bhh;  ma.hslot = hslot;  ma.states = states;
  ma.ids = ids;      ma.sorted = sorted;
  ma.Whe = c_Whe;    ma.bhe = c_bhe;  ma.hs = hs;
  ma.Wq = c_Wq;      ma.bq = c_bq;    ma.qb = qb;
  ma.Wk = c_Wk;      ma.bk = c_bk;    ma.kb = kb;
  ma.Wg = c_Wg;      ma.bg = c_bg;    ma.gws = gws;
  ma.zbias = zbias;  ma.scores = scores;
  ma.ctr = ctr;
  mega_kernel<<<dim3(256), dim3(1024), 0, stream>>>(ma);

  // heavy streaming stays OUT of the gru shadow (v14 lesson)
  gemm_v<<<dim3(16, V_ / 128), dim3(256), 0, stream>>>(hs, c_emb, c_ob, out, E_, V_);
  attn_scatter_kernel<<<dim3(S_, B_), dim3(256), 0, stream>>>(scores, gws, scal, sorted, out);
}

// Round 15
// 2565.374 us; speedup vs baseline: 1.8401x; 1.2552x over previous
//
#include <hip/hip_runtime.h>
#include <stdint.h>

#define V_ 32000
#define E_ 512
#define H_ 1024
#define M_ 256
#define B_ 2
#define S_ 1024
#define GC_ 24

typedef unsigned short u16;
typedef unsigned int u32;
typedef unsigned long long u64;

typedef __attribute__((ext_vector_type(8))) short short8;
typedef __attribute__((ext_vector_type(4))) float floatx4;
typedef __attribute__((ext_vector_type(2))) float floatx2;
typedef __attribute__((ext_vector_type(2))) _Float16 halfx2;

__device__ __forceinline__ float bf2f(u16 u){ return __uint_as_float(((u32)u) << 16); }
__device__ __forceinline__ float bflo(u32 u){ return __uint_as_float(u << 16); }
__device__ __forceinline__ float bfhi(u32 u){ return __uint_as_float(u & 0xffff0000u); }
__device__ __forceinline__ u16 f2bf(float f){
  u32 u = __float_as_uint(f);
  u32 r = (u + 0x7fffu + ((u >> 16) & 1u)) >> 16;
  return (u16)r;
}
__device__ __forceinline__ float sigm(float x){ return 1.f / (1.f + __expf(-x)); }

// 2-wide f16 dot product accumulating into f32 (v_dot2_f32_f16); graceful fallback.
__device__ __forceinline__ float dot2f16(u32 a, u32 b, float c){
#if __has_builtin(__builtin_amdgcn_fdot2)
  return __builtin_amdgcn_fdot2(__builtin_bit_cast(halfx2, a),
                                __builtin_bit_cast(halfx2, b), c, false);
#else
  halfx2 av = __builtin_bit_cast(halfx2, a);
  halfx2 bv = __builtin_bit_cast(halfx2, b);
  return fmaf((float)av.y, (float)bv.y, fmaf((float)av.x, (float)bv.x, c));
#endif
}

// async global->LDS 16B (wave-uniform LDS base + lane*16 scatter; per-lane global src)
__device__ __forceinline__ void gload_lds16(const void* g, void* l){
  __builtin_amdgcn_global_load_lds(
      (const __attribute__((address_space(1))) void*)g,
      (__attribute__((address_space(3))) void*)l, 16, 0, 0);
}

// ---------------- dtype probe: low-u16-as-bf16 plausibility test on emb ----------------
__global__ __launch_bounds__(64) void detect_kernel(const u32* __restrict__ emb,
    int* __restrict__ flag, float* __restrict__ scal,
    const void* __restrict__ lam, const void* __restrict__ ms)
{
  int lane = threadIdx.x;
  int c = 0;
  for (int i = lane; i < 256; i += 64){
    u32 w = emb[i];
    float a = fabsf(__uint_as_float((w & 0xffffu) << 16));
    if (a > 1e-5f && a < 1.0f) c++;
  }
  #pragma unroll
  for (int o = 32; o; o >>= 1) c += __shfl_down(c, o, 64);
  if (lane == 0){
    int isf32 = (c < 128) ? 1 : 0;
    *flag = isf32;
    if (isf32) scal[0] = ((const float*)lam)[0];
    else {
      float v = bf2f(((const u16*)lam)[0]);
      scal[0] = (fabsf(v) <= 4.0f) ? v : ((const float*)lam)[0];
    }
    if (isf32) scal[1] = ((const float*)ms)[0];
    else {
      u16 a = ((const u16*)ms)[0];
      float v = bf2f(a);
      scal[1] = (a != 0 && fabsf(v) > 1e-4f && fabsf(v) < 1e4f) ? v : ((const float*)ms)[0];
    }
  }
}

// ---------------- merged canonicalization: all 15 tensors in ONE launch ----------------
struct ConvArgs { const void* s[15]; };

#define CONV_TOTAL 22191385
__global__ __launch_bounds__(256) void convall_kernel(ConvArgs a, char* __restrict__ ws,
                                                      const int* __restrict__ flag)
{
  static const int    ns[15]    = {16384000, 1572864, 3145728, 262144, 262144, 1024,
                                   524288, 3072, 3072, 256, 256, 1, 512, 32000, 24};
  static const size_t doffs[15] = {33280, 32801280, 35947008, 42238464, 42762752,
                                   43287040, 43289088, 44337664, 44343808, 44349952,
                                   44350464, 44350976, 44351232, 44352256, 44416512};
  int gid = blockIdx.x * 256 + threadIdx.x;
  if (gid >= CONV_TOTAL) return;
  int isf32 = *flag;
  int seg = -1, r = gid;
  #pragma unroll
  for (int k = 0; k < 15; k++){
    if (seg < 0){ if (r < ns[k]) seg = k; else r -= ns[k]; }
  }
  const void* src = a.s[seg];
  u16* dst = (u16*)(ws + doffs[seg]);
  if (seg == 2){   // W_hh -> f16 (GRU dot2 path)
    float v = isf32 ? ((const float*)src)[r] : bf2f(((const u16*)src)[r]);
    dst[r] = __builtin_bit_cast(u16, (_Float16)v);
  } else {         // bf16 canonical
    dst[r] = isf32 ? f2bf(((const float*)src)[r]) : ((const u16*)src)[r];
  }
}

// ---------------- smear: x' = emb[ids]; x'[t] += lam*sigmoid(x[t,:24]@smW)*x[t-1] ----------------
__global__ __launch_bounds__(64) void smear_kernel(const int* __restrict__ ids,
    const u16* __restrict__ emb, const u16* __restrict__ smW,
    const float* __restrict__ scal, u16* __restrict__ xs)
{
  int row = blockIdx.x;                 // b*S + t
  int t = row & (S_ - 1);
  int lane = threadIdx.x;
  int id = ids[row];
  const u16* er = emb + (size_t)id * E_;
  float sg = 0.f;
  if (t > 0){
    float p = 0.f;
    if (lane < GC_) p = bf2f(er[lane]) * bf2f(smW[lane]);
    #pragma unroll
    for (int o = 32; o; o >>= 1) p += __shfl_down(p, o, 64);
    float dot = __shfl(p, 0, 64);
    sg = scal[0] * sigm(dot);
  }
  uint4 cur = ((const uint4*)er)[lane];
  uint4 outv = cur;
  if (t > 0){
    const u16* ep = emb + (size_t)ids[row - 1] * E_;
    uint4 prv = ((const uint4*)ep)[lane];
    const u16* cu = (const u16*)&cur;
    const u16* pu = (const u16*)&prv;
    u16* po = (u16*)&outv;
    #pragma unroll
    for (int j = 0; j < 8; j++) po[j] = f2bf(bf2f(cu[j]) + sg * bf2f(pu[j]));
  }
  ((uint4*)(xs + (size_t)row * E_))[lane] = outv;
}

// ---------------- generic MFMA GEMM: C(M,N) = A(M,K) * Bm(N,K)^T + bias(N) ----------------
template<bool OUT_BF16>
__global__ __launch_bounds__(256) void gemm_bt(
    const u16* __restrict__ A, const u16* __restrict__ Bm,
    const u16* __restrict__ bias, void* __restrict__ Cout,
    int K, int Ndim)
{
  int wave = threadIdx.x >> 6, lane = threadIdx.x & 63;
  int wm = wave >> 1, wn = wave & 1;
  int m0 = blockIdx.y * 128 + wm * 64;
  int n0 = blockIdx.x * 128 + wn * 64;
  int lrow = lane & 15, lq = lane >> 4;
  floatx4 acc[4][4];
  #pragma unroll
  for (int i = 0; i < 4; i++)
    #pragma unroll
    for (int j = 0; j < 4; j++) acc[i][j] = (floatx4)0.f;
  const u16* Ab = A + (size_t)(m0 + lrow) * K + lq * 8;
  const u16* Bb = Bm + (size_t)(n0 + lrow) * K + lq * 8;
  for (int k0 = 0; k0 < K; k0 += 32){
    short8 af[4], bfr[4];
    #pragma unroll
    for (int tt = 0; tt < 4; tt++)
      af[tt] = *(const short8*)(Ab + (size_t)tt * 16 * K + k0);
    #pragma unroll
    for (int tt = 0; tt < 4; tt++)
      bfr[tt] = *(const short8*)(Bb + (size_t)tt * 16 * K + k0);
    #pragma unroll
    for (int im = 0; im < 4; im++)
      #pragma unroll
      for (int in = 0; in < 4; in++)
        acc[im][in] = __builtin_amdgcn_mfma_f32_16x16x32_bf16(af[im], bfr[in], acc[im][in], 0, 0, 0);
  }
  #pragma unroll
  for (int in = 0; in < 4; in++){
    int n = n0 + in * 16 + lrow;
    float bv = bf2f(bias[n]);
    #pragma unroll
    for (int im = 0; im < 4; im++){
      int mb = m0 + im * 16 + lq * 4;
      #pragma unroll
      for (int r = 0; r < 4; r++){
        float v = acc[im][in][r] + bv;
        size_t off = (size_t)(mb + r) * Ndim + n;
        if (OUT_BF16) ((u16*)Cout)[off] = f2bf(v);
        else          ((float*)Cout)[off] = v;
      }
    }
  }
}

// ---------------- LDS-staged MFMA GEMM (transposed block map) for the big V-GEMM ----------------
// M-tile <- blockIdx.x (16), N-tile <- blockIdx.y (250): 16 consecutive blocks share
// one emb B-tile -> emb read once from HBM. Post-kernel (v14/v15: any concurrent
// streaming during the GRU inflates its sync RTT and loses).
__global__ __launch_bounds__(256) void gemm_v(
    const u16* __restrict__ A, const u16* __restrict__ Bm,
    const u16* __restrict__ bias, float* __restrict__ Cout,
    int K, int Ndim)
{
  __shared__ u16 la[128 * 32];
  __shared__ u16 lb[128 * 32];
  int wave = threadIdx.x >> 6, lane = threadIdx.x & 63;
  int wm = wave >> 1, wn = wave & 1;
  int tm0 = blockIdx.x * 128, tn0 = blockIdx.y * 128;
  int m0 = tm0 + wm * 64;
  int n0 = tn0 + wn * 64;
  int lrow = lane & 15, lq = lane >> 4;
  floatx4 acc[4][4];
  #pragma unroll
  for (int i = 0; i < 4; i++)
    #pragma unroll
    for (int j = 0; j < 4; j++) acc[i][j] = (floatx4)0.f;

  const int o = wave * 1024 + lane * 16;
  for (int k0 = 0; k0 < K; k0 += 32){
    #pragma unroll
    for (int j = 0; j < 2; j++){
      int oo = o + j * 4096;
      int row = oo >> 6;
      int ce  = (oo & 63) >> 1;
      gload_lds16(&A[(size_t)(tm0 + row) * K + k0 + ce],  &la[(wave * 1024 + j * 4096) >> 1]);
      gload_lds16(&Bm[(size_t)(tn0 + row) * K + k0 + ce], &lb[(wave * 1024 + j * 4096) >> 1]);
    }
    __syncthreads();
    short8 af[4], bfr[4];
    #pragma unroll
    for (int tt = 0; tt < 4; tt++)
      af[tt] = *(const short8*)&la[(wm * 64 + tt * 16 + lrow) * 32 + lq * 8];
    #pragma unroll
    for (int tt = 0; tt < 4; tt++)
      bfr[tt] = *(const short8*)&lb[(wn * 64 + tt * 16 + lrow) * 32 + lq * 8];
    #pragma unroll
    for (int im = 0; im < 4; im++)
      #pragma unroll
      for (int in = 0; in < 4; in++)
        acc[im][in] = __builtin_amdgcn_mfma_f32_16x16x32_bf16(af[im], bfr[in], acc[im][in], 0, 0, 0);
    __syncthreads();
  }
  #pragma unroll
  for (int in = 0; in < 4; in++){
    int n = n0 + in * 16 + lrow;
    float bv = bf2f(bias[n]);
    #pragma unroll
    for (int im = 0; im < 4; im++){
      int mb = m0 + im * 16 + lq * 4;
      #pragma unroll
      for (int r = 0; r < 4; r++)
        Cout[(size_t)(mb + r) * Ndim + n] = acc[im][in][r] + bv;
    }
  }
}

// ---------------- GRU persistent scan: XCD-confined batch placement (v16) ----------------
// v13 math byte-identical; only the blockIdx->(b,ibase) mapping changes.
// Grid 256 (1 WG/CU). With round-robin dispatch (blockIdx%8 -> XCD, m09/m157),
// xcd = blockIdx&7: gru WGs are xcd<2 with b=xcd, slot=blockIdx>>3 (32 per batch =
// exactly one XCD's 32 CUs). All hslot[*][b] traffic then stays inside one XCD's L2
// -> publish/poll RTT drops from fabric (~900cy) to local L2 (~250cy). Sort rides
// on xcd==2, slot<2; all other WGs exit. Placement is a perf heuristic only (G16):
// wrong mapping => baseline speed, same correctness.
__global__ __launch_bounds__(1024) void gru_kernel(
    const float* __restrict__ xg, const u16* __restrict__ W_hh,
    const u16* __restrict__ b_hh, u32* __restrict__ hslot,
    u16* __restrict__ states, const int* __restrict__ ids, int* __restrict__ sorted)
{
  const int xcd  = blockIdx.x & 7;
  const int slot = blockIdx.x >> 3;     // 0..31
  const int tid = threadIdx.x;

  __shared__ int arr[S_];               // sort WGs only
  if (xcd == 2){
    if (slot < 2){
      int b = slot;
      arr[tid] = (ids[b * S_ + tid] << 11) | tid;
      __syncthreads();
      for (int k = 2; k <= S_; k <<= 1){
        for (int j = k >> 1; j > 0; j >>= 1){
          int ixj = tid ^ j;
          if (ixj > tid){
            int a = arr[tid], c = arr[ixj];
            bool dir = (tid & k) == 0;
            if (dir ? (a > c) : (a < c)){ arr[tid] = c; arr[ixj] = a; }
          }
          __syncthreads();
        }
      }
      sorted[b * S_ + tid] = arr[tid];
    }
    return;
  }
  if (xcd >= 2) return;

  const int b = xcd;                    // batch confined to this XCD
  const int ibase = slot * 32;
  const int kg = tid >> 5;              // 32-k chunk [0,32); uniform per half-wave
  const int il = tid & 31;
  const int i = ibase + il;             // output this thread contributes to
  const int w = tid >> 6;               // wave id [0,16)

  __shared__ u32   lds_hpk[2][H_ / 2];  // packed f16 pairs of h (parity-dbuf)
  __shared__ float red[3][16][32];      // cross-wave partials (barrier-protected)

  // resident weights: 3 gates x 32 k f16 for (output i, k-chunk kg)
  uint4 Wv[3][4];
  #pragma unroll
  for (int g = 0; g < 3; g++){
    const uint4* p = (const uint4*)(W_hh + ((size_t)(g * H_ + i)) * H_ + kg * 32);
    #pragma unroll
    for (int q = 0; q < 4; q++) Wv[g][q] = p[q];
  }

  // tail-only state (wave 0, lanes 0-31): h_old, biases, xg(t) in registers
  float ho = 0.f, xr0 = 0.f, xz0 = 0.f, xn0 = 0.f, bh0 = 0.f, bh1 = 0.f, bh2 = 0.f;
  if (tid < 32){
    bh0 = bf2f(b_hh[ibase + tid]);
    bh1 = bf2f(b_hh[H_ + ibase + tid]);
    bh2 = bf2f(b_hh[2 * H_ + ibase + tid]);
    size_t base = ((size_t)(b * S_)) * 3072 + ibase + tid;
    xr0 = xg[base]; xz0 = xg[base + 1024]; xn0 = xg[base + 2048];
  }

  for (int t = 0; t < S_; t++){
    const int p = t & 1;
    // ---- poll + stage: 512 lanes, one u64 (2 tagged-u32 slots) each ----
    if (tid < 512){
      const u64* rp = (const u64*)(hslot + ((size_t)((p ^ 1) * B_ + b)) * H_) + tid;
      const u32 tg = (u32)t;
      u64 u0;
      do {
        u0 = __hip_atomic_load(rp, __ATOMIC_RELAXED, __HIP_MEMORY_SCOPE_AGENT);
      } while ((((u32)(u0 >> 16) & 0xffffu) != tg) | (((u32)(u0 >> 48)) != tg));
      lds_hpk[p][tid] = ((u32)u0 & 0xffffu) | (((u32)(u0 >> 32)) << 16);
    }
    __syncthreads();
    // ---- matvec partials: 48 dot2 over this thread's 32-k chunk (broadcast reads) ----
    const u32* hp = &lds_hpk[p][kg * 16];
    float pr = 0.f, pz = 0.f, pn = 0.f;
    #pragma unroll
    for (int q = 0; q < 4; q++){
      uint4 wr = Wv[0][q], wz = Wv[1][q], wn4 = Wv[2][q];
      u32 cr[4] = {wr.x, wr.y, wr.z, wr.w};
      u32 cz[4] = {wz.x, wz.y, wz.z, wz.w};
      u32 cn[4] = {wn4.x, wn4.y, wn4.z, wn4.w};
      #pragma unroll
      for (int e = 0; e < 4; e++){
        u32 h2 = hp[q * 4 + e];
        pr = dot2f16(cr[e], h2, pr);
        pz = dot2f16(cz[e], h2, pz);
        pn = dot2f16(cn[e], h2, pn);
      }
    }
    // combine the wave's two 32-k chunks, write per-wave partials
    pr += __shfl_xor(pr, 32, 64);
    pz += __shfl_xor(pz, 32, 64);
    pn += __shfl_xor(pn, 32, 64);
    if ((tid & 63) < 32){
      red[0][w][il] = pr; red[1][w][il] = pz; red[2][w][il] = pn;
    }
    __syncthreads();
    // ---- tail: wave 0 lanes 0-31 finalize; publish FIRST, then states/prefetch ----
    if (tid < 32){
      __builtin_amdgcn_s_setprio(1);
      float hr = 0.f, hz = 0.f, hn = 0.f;
      #pragma unroll
      for (int ww = 0; ww < 16; ww++){
        hr += red[0][ww][tid]; hz += red[1][ww][tid]; hn += red[2][ww][tid];
      }
      float r = sigm(xr0 + hr + bh0);
      float z = sigm(xz0 + hz + bh1);
      float xx = xn0 + r * (hn + bh2);
      float ax = fabsf(xx);
      float et = __expf(-2.f * ax);                     // overflow-safe fast tanh
      float n = copysignf((1.f - et) * __builtin_amdgcn_rcpf(1.f + et), xx);
      float hnew = (1.f - z) * n + z * ho;
      ho = hnew;
      u16 h16 = __builtin_bit_cast(u16, (_Float16)hnew);
      u32 tgv = (((u32)(t + 1)) << 16) | (u32)h16;
      __hip_atomic_store(&hslot[((size_t)(p * B_ + b)) * H_ + ibase + tid], tgv,
                         __ATOMIC_RELAXED, __HIP_MEMORY_SCOPE_AGENT);
      __builtin_amdgcn_s_setprio(0);
      states[((size_t)(b * S_ + t)) * H_ + ibase + tid] = f2bf(hnew);
      if (t + 1 < S_){
        size_t base = ((size_t)(b * S_ + t + 1)) * 3072 + ibase + tid;
        xr0 = xg[base]; xz0 = xg[base + 1024]; xn0 = xg[base + 2048];
      }
    }
  }
}

// ---------------- g gate: sigmoid(states @ Wg + bg) ----------------
__global__ __launch_bounds__(256) void gk_kernel(const u16* __restrict__ states,
    const u16* __restrict__ Wg, const u16* __restrict__ bg, float* __restrict__ gws)
{
  int row = blockIdx.x * 4 + (threadIdx.x >> 6);
  int lane = threadIdx.x & 63;
  const u16* sr = states + (size_t)row * H_;
  float p = 0.f;
  #pragma unroll
  for (int j = 0; j < 16; j++){
    int c = j * 64 + lane;
    p += bf2f(sr[c]) * bf2f(Wg[c]);
  }
  #pragma unroll
  for (int o = 32; o; o >>= 1) p += __shfl_xor(p, o, 64);
  if (lane == 0) gws[row] = sigm(p + bf2f(bg[0]));
}

// ---------------- fused attention + scatter (runs AFTER gemm_v) ----------------
__global__ __launch_bounds__(256) void attn_scatter_kernel(
    const float* __restrict__ scores, const float* __restrict__ gws,
    const float* __restrict__ scal, const int* __restrict__ sorted,
    float* __restrict__ out)
{
  int s = blockIdx.x, b = blockIdx.y;
  if (s == 0) return;
  int tid = threadIdx.x;
  __shared__ float grow[S_];
  __shared__ int   sb[S_];
  __shared__ float rbm[4], rbs[4];
  const float* srow = scores + ((size_t)(b * S_ + s)) * S_;
  #pragma unroll
  for (int r = 0; r < 4; r++) sb[tid + 256 * r] = sorted[b * S_ + tid + 256 * r];
  float myS[4];
  float lmax = -1e30f;
  #pragma unroll
  for (int r = 0; r < 4; r++){
    int t = tid + 256 * r;
    if (t < s){
      float d = srow[t] * 0.0625f;       // 1/sqrt(256)
      myS[r] = d;
      lmax = fmaxf(lmax, d);
    }
  }
  #pragma unroll
  for (int o = 32; o; o >>= 1) lmax = fmaxf(lmax, __shfl_xor(lmax, o, 64));
  if ((tid & 63) == 0) rbm[tid >> 6] = lmax;
  __syncthreads();
  float gmax = fmaxf(fmaxf(rbm[0], rbm[1]), fmaxf(rbm[2], rbm[3]));
  float lsum = 0.f;
  #pragma unroll
  for (int r = 0; r < 4; r++){
    int t = tid + 256 * r;
    if (t < s){ myS[r] = __expf(myS[r] - gmax); lsum += myS[r]; }
  }
  #pragma unroll
  for (int o = 32; o; o >>= 1) lsum += __shfl_xor(lsum, o, 64);
  if ((tid & 63) == 0) rbs[tid >> 6] = lsum;
  __syncthreads();
  float gsum = rbs[0] + rbs[1] + rbs[2] + rbs[3];
  float fac = gws[b * S_ + s] * scal[1] / gsum;
  #pragma unroll
  for (int r = 0; r < 4; r++){
    int t = tid + 256 * r;
    if (t < s) grow[t] = myS[r] * fac;
  }
  __syncthreads();
  float* orow = out + ((size_t)(b * S_ + s)) * V_;
  #pragma unroll
  for (int r = 0; r < 4; r++){
    int e = tid + 256 * r;
    int pk = sb[e];
    int v = pk >> 11;
    if (e > 0 && (sb[e - 1] >> 11) == v) continue;   // only leaders
    float sum = 0.f; bool any = false;
    for (int j = e; j < S_; j++){
      int pj = sb[j];
      if ((pj >> 11) != v) break;
      int t = pj & 2047;
      if (t < s){ sum += grow[t]; any = true; }
    }
    if (any) orow[v] += sum;
  }
}

extern "C" void kernel_launch(void* const* d_in, const int* in_sizes, int n_in,
                              void* d_out, int out_size, void* d_ws, size_t ws_size,
                              hipStream_t stream)
{
  const int*  ids   = (const int*)d_in[0];
  const void* emb   = d_in[1];
  const void* W_ih  = d_in[2];
  const void* W_hh  = d_in[3];
  const void* b_ih  = d_in[4];
  const void* b_hh  = d_in[5];
  const void* Wq    = d_in[6];
  const void* bq    = d_in[7];
  const void* Wk    = d_in[8];
  const void* bk    = d_in[9];
  const void* Wg    = d_in[10];
  const void* bg    = d_in[11];
  const void* Whe   = d_in[12];
  const void* bhe   = d_in[13];
  const void* obias = d_in[14];
  const void* ms    = d_in[15];
  const void* smW   = d_in[16];
  const void* lam   = d_in[17];
  (void)in_sizes; (void)n_in; (void)out_size; (void)ws_size;

  char* ws = (char*)d_ws;
  int*   flag   = (int*)(ws + 0);
  float* scal   = (float*)(ws + 256);
  u32*   hslot  = (u32*)(ws + 512);        // [2][B][H] tagged-f16 u32 slots (16 KB)
  u16*   zbias  = (u16*)(ws + 16896);      // 2 KB of bf16 zeros (scores-GEMM bias)
  u16*   c_emb  = (u16*)(ws + 33280);
  u16*   c_Wih  = (u16*)(ws + 32801280);
  u16*   c_Whh  = (u16*)(ws + 35947008);   // f16 content (GRU dot2 path)
  u16*   c_Wq   = (u16*)(ws + 42238464);
  u16*   c_Wk   = (u16*)(ws + 42762752);
  u16*   c_Wg   = (u16*)(ws + 43287040);
  u16*   c_Whe  = (u16*)(ws + 43289088);
  u16*   c_bih  = (u16*)(ws + 44337664);
  u16*   c_bhh  = (u16*)(ws + 44343808);
  u16*   c_bq   = (u16*)(ws + 44349952);
  u16*   c_bk   = (u16*)(ws + 44350464);
  u16*   c_bg   = (u16*)(ws + 44350976);
  u16*   c_bhe  = (u16*)(ws + 44351232);
  u16*   c_ob   = (u16*)(ws + 44352256);
  u16*   c_smW  = (u16*)(ws + 44416512);
  u16*   xs     = (u16*)(ws + 44416768);
  float* xg     = (float*)(ws + 46513920);
  u16*   states = (u16*)(ws + 71679744);
  u16*   hs     = (u16*)(ws + 75874048);
  u16*   qb     = (u16*)(ws + 77971200);
  u16*   kb     = (u16*)(ws + 79019776);
  float* gws    = (float*)(ws + 80068352);
  int*   sorted = (int*)(ws + 88465152);
  float* scores = xg;                      // xg region dead after gru; reuse (8.4 MB)
  float* out = (float*)d_out;

  hipMemsetAsync(hslot, 0, 16384, stream);   // h0 = 0 with tag 0
  hipMemsetAsync(zbias, 0, 2048, stream);    // zero bias for scores GEMM
  detect_kernel<<<dim3(1), dim3(64), 0, stream>>>((const u32*)emb, flag, scal, lam, ms);

  // single merged conversion launch
  ConvArgs ca;
  ca.s[0] = emb;  ca.s[1] = W_ih; ca.s[2] = W_hh; ca.s[3] = Wq;   ca.s[4] = Wk;
  ca.s[5] = Wg;   ca.s[6] = Whe;  ca.s[7] = b_ih; ca.s[8] = b_hh; ca.s[9] = bq;
  ca.s[10] = bk;  ca.s[11] = bg;  ca.s[12] = bhe; ca.s[13] = obias; ca.s[14] = smW;
  convall_kernel<<<dim3((CONV_TOTAL + 255) / 256), dim3(256), 0, stream>>>(ca, ws, flag);

  smear_kernel<<<dim3(B_ * S_), dim3(64), 0, stream>>>(ids, c_emb, c_smW, scal, xs);
  gemm_bt<false><<<dim3(3072 / 128, 2048 / 128), dim3(256), 0, stream>>>(xs, c_Wih, c_bih, (void*)xg, E_, 3072);
  // gru with XCD-confined batch placement (grid 256; inactive WGs exit) + piggybacked sort
  gru_kernel<<<dim3(256), dim3(1024), 0, stream>>>(xg, c_Whh, c_bhh, hslot, states, ids, sorted);
  gemm_bt<true><<<dim3(512 / 128, 16), dim3(256), 0, stream>>>(states, c_Whe, c_bhe, (void*)hs, H_, 512);
  gemm_bt<true><<<dim3(256 / 128, 16), dim3(256), 0, stream>>>(states, c_Wq, c_bq, (void*)qb, H_, 256);
  gemm_bt<true><<<dim3(256 / 128, 16), dim3(256), 0, stream>>>(states, c_Wk, c_bk, (void*)kb, H_, 256);
  // scores[b] = q[b] @ k[b]^T (fp32, zero bias) via MFMA
  gemm_bt<false><<<dim3(S_ / 128, S_ / 128), dim3(256), 0, stream>>>(qb, kb, zbias, (void*)scores, M_, S_);
  gemm_bt<false><<<dim3(S_ / 128, S_ / 128), dim3(256), 0, stream>>>(qb + (size_t)S_ * M_, kb + (size_t)S_ * M_,
                                                                     zbias, (void*)(scores + (size_t)S_ * S_), M_, S_);
  gk_kernel<<<dim3(512), dim3(256), 0, stream>>>(states, c_Wg, c_bg, gws);
  // big V-GEMM (transposed block mapping: grid (16, 250), emb B-panel read once)
  gemm_v<<<dim3(16, V_ / 128), dim3(256), 0, stream>>>(hs, c_emb, c_ob, out, E_, V_);
  // fused attention+scatter adds gated contributions onto the final logits
  attn_scatter_kernel<<<dim3(S_, B_), dim3(256), 0, stream>>>(scores, gws, scal, sorted, out);
}